// Round 10
// baseline (244.487 us; speedup 1.0000x reference)
//
#include <hip/hip_runtime.h>
#include <math.h>

#define BH  16384   // half batch
#define B2  32768
#define DIM 256
#define KC  1024    // clusters

typedef __bf16 bf16x8 __attribute__((ext_vector_type(8)));
typedef float  f32x4  __attribute__((ext_vector_type(4)));

__device__ __forceinline__ unsigned short f2bf(float f) {
  unsigned int u = __float_as_uint(f);
  u += 0x7FFFu + ((u >> 16) & 1u);   // RNE; inputs are finite
  return (unsigned short)(u >> 16);
}

__device__ __forceinline__ float vsqrt(float x) {
  float r; asm("v_sqrt_f32 %0, %1" : "=v"(r) : "v"(x)); return r;
}

__device__ __forceinline__ void gld_lds16(const void* g, void* l) {
  __builtin_amdgcn_global_load_lds(
      (const __attribute__((address_space(1))) void*)g,
      (__attribute__((address_space(3))) void*)l, 16, 0, 0);
}

// one wave per row: l2-normalize and convert to bf16.
// Blocks 0..15 also zero colsum; block 16 zeros out.
__global__ void norm_rows_kernel(const float* __restrict__ z,
                                 const float* __restrict__ p,
                                 const float* __restrict__ c,
                                 unsigned short* __restrict__ Xn,
                                 unsigned short* __restrict__ Cn,
                                 float* __restrict__ colsum,
                                 float* __restrict__ out) {
  if (blockIdx.x < 16) colsum[blockIdx.x * 256 + threadIdx.x] = 0.0f;
  if (blockIdx.x == 16 && threadIdx.x == 0) out[0] = 0.0f;

  int wave = threadIdx.x >> 6;
  int lane = threadIdx.x & 63;
  int row  = blockIdx.x * 4 + wave;          // 0 .. 66559
  const float* src; unsigned short* dst; int r;
  if (row < B2)        { src = z; dst = Xn; r = row; }
  else if (row < 2*B2) { src = p; dst = Xn + (size_t)B2 * DIM; r = row - B2; }
  else                 { src = c; dst = Cn; r = row - 2*B2; }
  float4 v = *reinterpret_cast<const float4*>(src + (size_t)r * DIM + lane * 4);
  float ss = v.x*v.x + v.y*v.y + v.z*v.z + v.w*v.w;
  #pragma unroll
  for (int m = 1; m < 64; m <<= 1) ss += __shfl_xor(ss, m);
  float inv = 1.0f / fmaxf(vsqrt(ss), 1e-12f);
  ushort4 o;
  o.x = f2bf(v.x * inv); o.y = f2bf(v.y * inv);
  o.z = f2bf(v.z * inv); o.w = f2bf(v.w * inv);
  *reinterpret_cast<ushort4*>(dst + (size_t)r * DIM + lane * 4) = o;
}

__global__ void fin_logC_kernel(const float* __restrict__ colsum,
                                float* __restrict__ logC) {
  int i = blockIdx.x * 256 + threadIdx.x;
  if (i < 4 * KC) logC[i] = 40.0f + __logf(colsum[i]);
}

// ---------------- 8-phase 256x256 GEMM (m201-style schedule) -------------
// 256 blocks x 512 threads; block tile 256(M) x 256(N); wave tile 128x64.
// K-chain: 16 tiles (4 mats x 4 BK64-steps); 8 iterations of 2 tiles.
// LDS: A buf0 @0, A buf1 @32768, B buf0 @65536, B buf1 @98304, LUT @131072.

#define SBAR() __builtin_amdgcn_sched_barrier(0)
#define BARR() __builtin_amdgcn_s_barrier()
#define VM6()  asm volatile("s_waitcnt vmcnt(6)" ::: "memory")

__global__ __launch_bounds__(512, 2)
void gemm8_kernel(const unsigned short* __restrict__ XA,  // [4][BH][DIM]
                  const unsigned short* __restrict__ Cn,  // [KC][DIM]
                  float* __restrict__ colsum,
                  unsigned char* __restrict__ S) {        // [4][BH][KC] u8
  __shared__ __align__(16) char lds[135168];
  float* lut4 = (float*)(lds + 131072);

  const int id = blockIdx.x;                 // 256
  const int wk = (id & 7) * 32 + (id >> 3);  // XCD-chunked, bijective
  const int panel = wk >> 2, col = wk & 3;
  const int tm0 = panel * 256, tn0 = col * 256;

  const int tid  = threadIdx.x;
  const int lane = tid & 63;
  const int wid  = tid >> 6;
  const int wm   = wid >> 2, wn = wid & 3;   // 2 x 4 wave grid
  const int l15  = lane & 15, l4 = lane >> 4;
  const int sw   = l15 & 7;
  const int slot4 = tid & 3;

  if (tid < 256) {
    float d = ((float)tid - 127.5f) * (1.0f / 255.0f);
    float L = 20.0f * vsqrt(2.0f - 2.0f * d);
    float v = __expf(L - 40.0f);
    ((float4*)lut4)[tid] = (float4){v, v, v, v};
  }

  // staging constants: half-tile = 128 rows x 128 B; 1024 slots of 16 B
  const int srow0 = tid >> 3,          sc0 = (tid & 7) ^ (srow0 & 7);
  const int srow1 = srow0 + 64,        sc1 = ((tid + 512) & 7) ^ (srow1 & 7);

#define ST_A(tile, half, dst) do {                                          \
    int tt_ = (tile) & 15;                                                  \
    const char* src_ = (const char*)XA + ((size_t)(tt_ >> 2) << 23)         \
        + (size_t)(tm0 + (half) * 128) * 512 + (tt_ & 3) * 128;             \
    gld_lds16(src_ + (size_t)srow0 * 512 + sc0 * 16,                        \
              lds + (dst) + tid * 16);                                      \
    gld_lds16(src_ + (size_t)srow1 * 512 + sc1 * 16,                        \
              lds + (dst) + (tid + 512) * 16);                              \
  } while (0)

#define ST_B(tile, half, dst) do {                                          \
    int tt_ = (tile) & 15;                                                  \
    const char* src_ = (const char*)Cn                                      \
        + (size_t)(tn0 + (half) * 128) * 512 + (tt_ & 3) * 128;             \
    gld_lds16(src_ + (size_t)srow0 * 512 + sc0 * 16,                        \
              lds + (dst) + tid * 16);                                      \
    gld_lds16(src_ + (size_t)srow1 * 512 + sc1 * 16,                        \
              lds + (dst) + (tid + 512) * 16);                              \
  } while (0)

  bf16x8 aR[8], bR0[4], bR1[4];
  f32x4  acc[8][4];

#define RD_A(base, ah) do {                                                 \
    _Pragma("unroll")                                                       \
    for (int f_ = 0; f_ < 4; ++f_) {                                        \
      int ra_ = wm * 128 + (ah) * 64 + f_ * 16 + l15;                       \
      _Pragma("unroll")                                                     \
      for (int kc_ = 0; kc_ < 2; ++kc_)                                     \
        aR[f_ * 2 + kc_] = *(const bf16x8*)(lds + (base) + ra_ * 128        \
            + (((kc_ * 4 + l4) ^ sw) << 4));                                \
    }                                                                       \
  } while (0)

#define RD_B(base, bh, bR) do {                                             \
    _Pragma("unroll")                                                       \
    for (int g_ = 0; g_ < 2; ++g_) {                                        \
      int rb_ = wn * 64 + (bh) * 32 + g_ * 16 + l15;                        \
      _Pragma("unroll")                                                     \
      for (int kc_ = 0; kc_ < 2; ++kc_)                                     \
        bR[g_ * 2 + kc_] = *(const bf16x8*)(lds + (base) + rb_ * 128        \
            + (((kc_ * 4 + l4) ^ sw) << 4));                                \
    }                                                                       \
  } while (0)

#define QUAD(ah, bh, bR) do {                                               \
    _Pragma("unroll")                                                       \
    for (int kc_ = 0; kc_ < 2; ++kc_)                                       \
      _Pragma("unroll")                                                     \
      for (int f_ = 0; f_ < 4; ++f_)                                        \
        _Pragma("unroll")                                                   \
        for (int g_ = 0; g_ < 2; ++g_)                                      \
          acc[(ah) * 4 + f_][(bh) * 2 + g_] =                               \
              __builtin_amdgcn_mfma_f32_16x16x32_bf16(                      \
                  aR[f_ * 2 + kc_], bR[g_ * 2 + kc_],                       \
                  acc[(ah) * 4 + f_][(bh) * 2 + g_], 0, 0, 0);              \
  } while (0)

#define SYNC_MFMA(ah, bh, bR) do {                                          \
    SBAR(); BARR(); SBAR();                                                 \
    __builtin_amdgcn_s_setprio(1);                                          \
    QUAD(ah, bh, bR);                                                       \
    __builtin_amdgcn_s_setprio(0);                                          \
    SBAR(); BARR();                                                         \
  } while (0)

  // prologue: tile0 fully + tile1 {A0,B0,B1}; tile1.A1 comes at it0-P1
  ST_A(0, 0, 0);            ST_A(0, 1, 16384);
  ST_B(0, 0, 65536);        ST_B(0, 1, 65536 + 16384);
  ST_A(1, 0, 32768);
  ST_B(1, 0, 65536 + 32768);
  ST_B(1, 1, 65536 + 32768 + 16384);
  __syncthreads();          // full drain once; also publishes LUT

  #pragma unroll 1
  for (int it = 0; it < 8; ++it) {
    const int t0 = 2 * it, t1 = t0 + 1;

    if ((it & 1) == 0) {
      #pragma unroll
      for (int fi = 0; fi < 8; ++fi)
        #pragma unroll
        for (int fj = 0; fj < 4; ++fj)
          acc[fi][fj] = (f32x4){0.f, 0.f, 0.f, 0.f};
    }

    // P1: tile t0 (buf0) q(0,0)
    RD_B(65536, 0, bR0); RD_A(0, 0);
    ST_A(t1, 1, 32768 + 16384);
    SYNC_MFMA(0, 0, bR0);
    // P2: q(0,1)
    RD_B(65536, 1, bR1);
    ST_A(t0 + 2, 0, 0);
    SYNC_MFMA(0, 1, bR1);
    // P3: q(1,1)
    RD_A(0, 1);
    ST_B(t0 + 2, 0, 65536);
    SYNC_MFMA(1, 1, bR1);
    // P4: q(1,0)  [bR0 from P1, aR from P3]
    ST_B(t0 + 2, 1, 65536 + 16384);
    VM6();
    SYNC_MFMA(1, 0, bR0);
    // P5: tile t1 (buf1) q(0,0)
    RD_B(65536 + 32768, 0, bR0); RD_A(32768, 0);
    ST_A(t0 + 2, 1, 16384);
    SYNC_MFMA(0, 0, bR0);
    // P6: q(0,1)
    RD_B(65536 + 32768, 1, bR1);
    ST_A(t1 + 2, 0, 32768);
    SYNC_MFMA(0, 1, bR1);
    // P7: q(1,1)
    RD_A(32768, 1);
    ST_B(t1 + 2, 0, 65536 + 32768);
    SYNC_MFMA(1, 1, bR1);
    // P8: q(1,0)
    ST_B(t1 + 2, 1, 65536 + 32768 + 16384);
    VM6();
    SYNC_MFMA(1, 0, bR0);

    if (it & 1) {
      // epilogue for mat = it>>1: quantize dot -> u8 store + LUT colsum
      const int mat = it >> 1;
      unsigned char* Sp = S + ((size_t)mat * BH + tm0) * KC + tn0;
      #pragma unroll
      for (int fj = 0; fj < 4; ++fj) {
        float cp = 0.0f;
        #pragma unroll
        for (int fi = 0; fi < 8; ++fi)
          #pragma unroll
          for (int i = 0; i < 4; ++i) {
            float v = fmaf(acc[fi][fj][i], 255.0f, 128.0f);
            v = fminf(fmaxf(v, 0.0f), 255.0f);
            unsigned e = (unsigned)v;
            cp += lut4[(e << 2) | slot4];
            int row  = wm * 128 + fi * 16 + l4 * 4 + i;
            int ccol = wn * 64 + fj * 16 + l15;
            Sp[(size_t)row * KC + ccol] = (unsigned char)e;
          }
        cp += __shfl_xor(cp, 16);
        cp += __shfl_xor(cp, 32);
        if (l4 == 0)
          atomicAdd(&colsum[mat * KC + tn0 + wn * 64 + fj * 16 + l15], cp);
      }
      VM6();   // drain epilogue stores; pending 6 newest remain in flight
    }
  }
}

// decode u8 -> G = L(d_e) - lc
__device__ __forceinline__ float decG(unsigned e, float lc) {
  float d = fmaf((float)e, 1.0f / 255.0f, -0.5f);
  float L = 20.0f * vsqrt(fmaf(-2.0f, d, 2.0f));
  return L - lc;
}

// one wave per row: stream 4 planes of S (u8), per-row loss; one global
// write per block (no hot atomics).
__global__ __launch_bounds__(256)
void pass2_mem_kernel(const unsigned char* __restrict__ S,
                      const float* __restrict__ logC,
                      float* __restrict__ rowv) {
  const int tid  = threadIdx.x;
  const int lane = tid & 63;
  const int wid  = tid >> 6;
  const int row  = blockIdx.x * 4 + wid;      // 4096 blocks -> BH rows
  const size_t plane = (size_t)BH * KC;
  const unsigned char* Sr = S + (size_t)row * KC;

  float dp1 = 0.f, dp2 = 0.f, dz1 = 0.f, dz2 = 0.f, nz1 = 0.f, nz2 = 0.f;

  #pragma unroll
  for (int it = 0; it < 2; ++it) {
    const int kb = it * 512 + lane * 8;
    uint2 vz1 = *reinterpret_cast<const uint2*>(Sr + 0 * plane + kb);
    uint2 vz2 = *reinterpret_cast<const uint2*>(Sr + 1 * plane + kb);
    uint2 vp1 = *reinterpret_cast<const uint2*>(Sr + 2 * plane + kb);
    uint2 vp2 = *reinterpret_cast<const uint2*>(Sr + 3 * plane + kb);

    float cz1[8], cz2[8], cp1[8], cp2[8];
    *reinterpret_cast<float4*>(&cz1[0]) = *reinterpret_cast<const float4*>(logC + 0 * KC + kb);
    *reinterpret_cast<float4*>(&cz1[4]) = *reinterpret_cast<const float4*>(logC + 0 * KC + kb + 4);
    *reinterpret_cast<float4*>(&cz2[0]) = *reinterpret_cast<const float4*>(logC + 1 * KC + kb);
    *reinterpret_cast<float4*>(&cz2[4]) = *reinterpret_cast<const float4*>(logC + 1 * KC + kb + 4);
    *reinterpret_cast<float4*>(&cp1[0]) = *reinterpret_cast<const float4*>(logC + 2 * KC + kb);
    *reinterpret_cast<float4*>(&cp1[4]) = *reinterpret_cast<const float4*>(logC + 2 * KC + kb + 4);
    *reinterpret_cast<float4*>(&cp2[0]) = *reinterpret_cast<const float4*>(logC + 3 * KC + kb);
    *reinterpret_cast<float4*>(&cp2[4]) = *reinterpret_cast<const float4*>(logC + 3 * KC + kb + 4);

    unsigned b1[8], b2[8];
    #pragma unroll
    for (int e = 0; e < 4; ++e) {
      b1[e]     = (vp1.x >> (8 * e)) & 0xffu;
      b1[e + 4] = (vp1.y >> (8 * e)) & 0xffu;
      b2[e]     = (vp2.x >> (8 * e)) & 0xffu;
      b2[e + 4] = (vp2.y >> (8 * e)) & 0xffu;
    }
    float tv[8];
    #pragma unroll
    for (int e = 0; e < 8; ++e) {
      float g1 = decG(b1[e], cp1[e]);
      float g2 = decG(b2[e], cp2[e]);
      dp1 += __expf(g1);
      dp2 += __expf(g2);
      tv[e] = g1 + g2;
    }
    #pragma unroll
    for (int e = 0; e < 4; ++e) {
      b1[e]     = (vz1.x >> (8 * e)) & 0xffu;
      b1[e + 4] = (vz1.y >> (8 * e)) & 0xffu;
      b2[e]     = (vz2.x >> (8 * e)) & 0xffu;
      b2[e + 4] = (vz2.y >> (8 * e)) & 0xffu;
    }
    #pragma unroll
    for (int e = 0; e < 8; ++e) {
      float e1 = __expf(decG(b1[e], cz1[e]));
      float e2 = __expf(decG(b2[e], cz2[e]));
      dz1 += e1; nz1 += e1 * tv[e];
      dz2 += e2; nz2 += e2 * tv[e];
    }
  }

  #pragma unroll
  for (int m = 1; m < 64; m <<= 1) {
    dp1 += __shfl_xor(dp1, m); dp2 += __shfl_xor(dp2, m);
    dz1 += __shfl_xor(dz1, m); dz2 += __shfl_xor(dz2, m);
    nz1 += __shfl_xor(nz1, m); nz2 += __shfl_xor(nz2, m);
  }

  __shared__ float red[4];
  if (lane == 0)
    red[wid] = nz1 / dz1 + nz2 / dz2 - 2.0f * (__logf(dp1) + __logf(dp2));
  __syncthreads();
  if (tid == 0)
    rowv[blockIdx.x] = red[0] + red[1] + red[2] + red[3];
}

// 4096 partials -> 16 blocks -> 16 atomics
__global__ void fin_reduce_kernel(const float* __restrict__ rowv,
                                  float* __restrict__ out) {
  int i = blockIdx.x * 256 + threadIdx.x;
  float v = rowv[i];
  #pragma unroll
  for (int m = 1; m < 64; m <<= 1) v += __shfl_xor(v, m);
  __shared__ float ws[4];
  int lane = threadIdx.x & 63, wid = threadIdx.x >> 6;
  if (lane == 0) ws[wid] = v;
  __syncthreads();
  if (threadIdx.x == 0)
    atomicAdd(out, (ws[0] + ws[1] + ws[2] + ws[3]) * (-1.0f / 65536.0f));
}

extern "C" void kernel_launch(void* const* d_in, const int* in_sizes, int n_in,
                              void* d_out, int out_size, void* d_ws, size_t ws_size,
                              hipStream_t stream) {
  const float* z = (const float*)d_in[0];
  const float* p = (const float*)d_in[1];
  const float* c = (const float*)d_in[2];
  char* ws = (char*)d_ws;
  // layout: XA bf16 33.55MB | Cn 0.5MB | colsum 16KB | logC 16KB |
  //         rowv 16KB | S u8 67.1MB
  unsigned short* Xn = (unsigned short*)(ws);
  unsigned short* Cn = (unsigned short*)(ws + 33554432);
  float* colsum = (float*)(ws + 34078720);
  float* logC   = (float*)(ws + 34095104);
  float* rowv   = (float*)(ws + 34111488);
  unsigned char* S = (unsigned char*)(ws + 34127872);
  float* out = (float*)d_out;

  norm_rows_kernel<<<16640, 256, 0, stream>>>(z, p, c, Xn, Cn, colsum, out);
  gemm8_kernel<<<256, 512, 0, stream>>>(Xn, Cn, colsum, S);
  fin_logC_kernel<<<16, 256, 0, stream>>>(colsum, logC);
  pass2_mem_kernel<<<4096, 256, 0, stream>>>(S, logC, rowv);
  fin_reduce_kernel<<<16, 256, 0, stream>>>(rowv, out);
}

// Round 11
// 243.245 us; speedup vs baseline: 1.0051x; 1.0051x over previous
//
#include <hip/hip_runtime.h>
#include <math.h>

#define BH  16384   // half batch
#define B2  32768
#define DIM 256
#define KC  1024    // clusters

typedef __bf16 bf16x8 __attribute__((ext_vector_type(8)));
typedef float  f32x4  __attribute__((ext_vector_type(4)));

__device__ __forceinline__ unsigned short f2bf(float f) {
  unsigned int u = __float_as_uint(f);
  u += 0x7FFFu + ((u >> 16) & 1u);   // RNE; inputs are finite
  return (unsigned short)(u >> 16);
}

__device__ __forceinline__ float vsqrt(float x) {
  float r; asm("v_sqrt_f32 %0, %1" : "=v"(r) : "v"(x)); return r;
}

__device__ __forceinline__ void gld_lds16(const void* g, void* l) {
  __builtin_amdgcn_global_load_lds(
      (const __attribute__((address_space(1))) void*)g,
      (__attribute__((address_space(3))) void*)l, 16, 0, 0);
}

// one wave per row: l2-normalize and convert to bf16.
// Blocks 0..15 also zero colsum; block 16 zeros out.
__global__ void norm_rows_kernel(const float* __restrict__ z,
                                 const float* __restrict__ p,
                                 const float* __restrict__ c,
                                 unsigned short* __restrict__ Xn,
                                 unsigned short* __restrict__ Cn,
                                 float* __restrict__ colsum,
                                 float* __restrict__ out) {
  if (blockIdx.x < 16) colsum[blockIdx.x * 256 + threadIdx.x] = 0.0f;
  if (blockIdx.x == 16 && threadIdx.x == 0) out[0] = 0.0f;

  int wave = threadIdx.x >> 6;
  int lane = threadIdx.x & 63;
  int row  = blockIdx.x * 4 + wave;          // 0 .. 66559
  const float* src; unsigned short* dst; int r;
  if (row < B2)        { src = z; dst = Xn; r = row; }
  else if (row < 2*B2) { src = p; dst = Xn + (size_t)B2 * DIM; r = row - B2; }
  else                 { src = c; dst = Cn; r = row - 2*B2; }
  float4 v = *reinterpret_cast<const float4*>(src + (size_t)r * DIM + lane * 4);
  float ss = v.x*v.x + v.y*v.y + v.z*v.z + v.w*v.w;
  #pragma unroll
  for (int m = 1; m < 64; m <<= 1) ss += __shfl_xor(ss, m);
  float inv = 1.0f / fmaxf(vsqrt(ss), 1e-12f);
  ushort4 o;
  o.x = f2bf(v.x * inv); o.y = f2bf(v.y * inv);
  o.z = f2bf(v.z * inv); o.w = f2bf(v.w * inv);
  *reinterpret_cast<ushort4*>(dst + (size_t)r * DIM + lane * 4) = o;
}

__global__ void fin_logC_kernel(const float* __restrict__ colsum,
                                float* __restrict__ logC) {
  int i = blockIdx.x * 256 + threadIdx.x;
  if (i < 4 * KC) logC[i] = 40.0f + __logf(colsum[i]);
}

// ---------------- 8-phase 256x256 GEMM (m201-style schedule) -------------
// 256 blocks x 512 threads; block tile 256(M) x 256(N); wave tile 128x64.
// K-chain: 16 tiles (4 mats x 4 BK64-steps); 8 iterations of 2 tiles.
// LDS: A buf0 @0, A buf1 @32768, B buf0 @65536, B buf1 @98304, LUT @131072.
// NOTE: 132KB LDS -> only 1 block/CU can fit; min-occupancy MUST be 1 or the
// allocator clamps VGPRs to 128 and spills the 128-reg accumulator (r10).

#define SBAR() __builtin_amdgcn_sched_barrier(0)
#define BARR() __builtin_amdgcn_s_barrier()
#define VM6()  asm volatile("s_waitcnt vmcnt(6)" ::: "memory")

__global__ __launch_bounds__(512, 1)
void gemm8_kernel(const unsigned short* __restrict__ XA,  // [4][BH][DIM]
                  const unsigned short* __restrict__ Cn,  // [KC][DIM]
                  float* __restrict__ colsum,
                  unsigned char* __restrict__ S) {        // [4][BH][KC] u8
  __shared__ __align__(16) char lds[135168];
  float* lut4 = (float*)(lds + 131072);

  const int id = blockIdx.x;                 // 256
  const int wk = (id & 7) * 32 + (id >> 3);  // XCD-chunked, bijective
  const int panel = wk >> 2, col = wk & 3;
  const int tm0 = panel * 256, tn0 = col * 256;

  const int tid  = threadIdx.x;
  const int lane = tid & 63;
  const int wid  = tid >> 6;
  const int wm   = wid >> 2, wn = wid & 3;   // 2 x 4 wave grid
  const int l15  = lane & 15, l4 = lane >> 4;
  const int sw   = l15 & 7;
  const int slot4 = tid & 3;

  if (tid < 256) {
    float d = ((float)tid - 127.5f) * (1.0f / 255.0f);
    float L = 20.0f * vsqrt(2.0f - 2.0f * d);
    float v = __expf(L - 40.0f);
    ((float4*)lut4)[tid] = (float4){v, v, v, v};
  }

  // staging constants: half-tile = 128 rows x 128 B; 1024 slots of 16 B
  const int srow0 = tid >> 3,          sc0 = (tid & 7) ^ (srow0 & 7);
  const int srow1 = srow0 + 64,        sc1 = ((tid + 512) & 7) ^ (srow1 & 7);

#define ST_A(tile, half, dst) do {                                          \
    int tt_ = (tile) & 15;                                                  \
    const char* src_ = (const char*)XA + ((size_t)(tt_ >> 2) << 23)         \
        + (size_t)(tm0 + (half) * 128) * 512 + (tt_ & 3) * 128;             \
    gld_lds16(src_ + (size_t)srow0 * 512 + sc0 * 16,                        \
              lds + (dst) + tid * 16);                                      \
    gld_lds16(src_ + (size_t)srow1 * 512 + sc1 * 16,                        \
              lds + (dst) + (tid + 512) * 16);                              \
  } while (0)

#define ST_B(tile, half, dst) do {                                          \
    int tt_ = (tile) & 15;                                                  \
    const char* src_ = (const char*)Cn                                      \
        + (size_t)(tn0 + (half) * 128) * 512 + (tt_ & 3) * 128;             \
    gld_lds16(src_ + (size_t)srow0 * 512 + sc0 * 16,                        \
              lds + (dst) + tid * 16);                                      \
    gld_lds16(src_ + (size_t)srow1 * 512 + sc1 * 16,                        \
              lds + (dst) + (tid + 512) * 16);                              \
  } while (0)

  bf16x8 aR[8], bR0[4], bR1[4];
  f32x4  acc[8][4];

#define RD_A(base, ah) do {                                                 \
    _Pragma("unroll")                                                       \
    for (int f_ = 0; f_ < 4; ++f_) {                                        \
      int ra_ = wm * 128 + (ah) * 64 + f_ * 16 + l15;                       \
      _Pragma("unroll")                                                     \
      for (int kc_ = 0; kc_ < 2; ++kc_)                                     \
        aR[f_ * 2 + kc_] = *(const bf16x8*)(lds + (base) + ra_ * 128        \
            + (((kc_ * 4 + l4) ^ sw) << 4));                                \
    }                                                                       \
  } while (0)

#define RD_B(base, bh, bR) do {                                             \
    _Pragma("unroll")                                                       \
    for (int g_ = 0; g_ < 2; ++g_) {                                        \
      int rb_ = wn * 64 + (bh) * 32 + g_ * 16 + l15;                        \
      _Pragma("unroll")                                                     \
      for (int kc_ = 0; kc_ < 2; ++kc_)                                     \
        bR[g_ * 2 + kc_] = *(const bf16x8*)(lds + (base) + rb_ * 128        \
            + (((kc_ * 4 + l4) ^ sw) << 4));                                \
    }                                                                       \
  } while (0)

#define QUAD(ah, bh, bR) do {                                               \
    _Pragma("unroll")                                                       \
    for (int kc_ = 0; kc_ < 2; ++kc_)                                       \
      _Pragma("unroll")                                                     \
      for (int f_ = 0; f_ < 4; ++f_)                                        \
        _Pragma("unroll")                                                   \
        for (int g_ = 0; g_ < 2; ++g_)                                      \
          acc[(ah) * 4 + f_][(bh) * 2 + g_] =                               \
              __builtin_amdgcn_mfma_f32_16x16x32_bf16(                      \
                  aR[f_ * 2 + kc_], bR[g_ * 2 + kc_],                       \
                  acc[(ah) * 4 + f_][(bh) * 2 + g_], 0, 0, 0);              \
  } while (0)

#define SYNC_MFMA(ah, bh, bR) do {                                          \
    SBAR(); BARR(); SBAR();                                                 \
    __builtin_amdgcn_s_setprio(1);                                          \
    QUAD(ah, bh, bR);                                                       \
    __builtin_amdgcn_s_setprio(0);                                          \
    SBAR(); BARR();                                                         \
  } while (0)

  // prologue: tile0 fully + tile1 {A0,B0,B1}; tile1.A1 comes at it0-P1
  ST_A(0, 0, 0);            ST_A(0, 1, 16384);
  ST_B(0, 0, 65536);        ST_B(0, 1, 65536 + 16384);
  ST_A(1, 0, 32768);
  ST_B(1, 0, 65536 + 32768);
  ST_B(1, 1, 65536 + 32768 + 16384);
  __syncthreads();          // full drain once; also publishes LUT

  #pragma unroll 1
  for (int it = 0; it < 8; ++it) {
    const int t0 = 2 * it, t1 = t0 + 1;

    if ((it & 1) == 0) {
      #pragma unroll
      for (int fi = 0; fi < 8; ++fi)
        #pragma unroll
        for (int fj = 0; fj < 4; ++fj)
          acc[fi][fj] = (f32x4){0.f, 0.f, 0.f, 0.f};
    }

    // P1: tile t0 (buf0) q(0,0)
    RD_B(65536, 0, bR0); RD_A(0, 0);
    ST_A(t1, 1, 32768 + 16384);
    SYNC_MFMA(0, 0, bR0);
    // P2: q(0,1)
    RD_B(65536, 1, bR1);
    ST_A(t0 + 2, 0, 0);
    SYNC_MFMA(0, 1, bR1);
    // P3: q(1,1)
    RD_A(0, 1);
    ST_B(t0 + 2, 0, 65536);
    SYNC_MFMA(1, 1, bR1);
    // P4: q(1,0)  [bR0 from P1, aR from P3]
    ST_B(t0 + 2, 1, 65536 + 16384);
    VM6();
    SYNC_MFMA(1, 0, bR0);
    // P5: tile t1 (buf1) q(0,0)
    RD_B(65536 + 32768, 0, bR0); RD_A(32768, 0);
    ST_A(t0 + 2, 1, 16384);
    SYNC_MFMA(0, 0, bR0);
    // P6: q(0,1)
    RD_B(65536 + 32768, 1, bR1);
    ST_A(t1 + 2, 0, 32768);
    SYNC_MFMA(0, 1, bR1);
    // P7: q(1,1)
    RD_A(32768, 1);
    ST_B(t1 + 2, 0, 65536 + 32768);
    SYNC_MFMA(1, 1, bR1);
    // P8: q(1,0)
    ST_B(t1 + 2, 1, 65536 + 32768 + 16384);
    VM6();
    SYNC_MFMA(1, 0, bR0);

    if (it & 1) {
      // epilogue for mat = it>>1: quantize dot -> u8 store + LUT colsum
      const int mat = it >> 1;
      unsigned char* Sp = S + ((size_t)mat * BH + tm0) * KC + tn0;
      #pragma unroll
      for (int fj = 0; fj < 4; ++fj) {
        float cp = 0.0f;
        #pragma unroll
        for (int fi = 0; fi < 8; ++fi)
          #pragma unroll
          for (int i = 0; i < 4; ++i) {
            float v = fmaf(acc[fi][fj][i], 255.0f, 128.0f);
            v = fminf(fmaxf(v, 0.0f), 255.0f);
            unsigned e = (unsigned)v;
            cp += lut4[(e << 2) | slot4];
            int row  = wm * 128 + fi * 16 + l4 * 4 + i;
            int ccol = wn * 64 + fj * 16 + l15;
            Sp[(size_t)row * KC + ccol] = (unsigned char)e;
          }
        cp += __shfl_xor(cp, 16);
        cp += __shfl_xor(cp, 32);
        if (l4 == 0)
          atomicAdd(&colsum[mat * KC + tn0 + wn * 64 + fj * 16 + l15], cp);
      }
      VM6();   // drain epilogue stores; pending 6 newest remain in flight
    }
  }
}

// decode u8 -> G = L(d_e) - lc
__device__ __forceinline__ float decG(unsigned e, float lc) {
  float d = fmaf((float)e, 1.0f / 255.0f, -0.5f);
  float L = 20.0f * vsqrt(fmaf(-2.0f, d, 2.0f));
  return L - lc;
}

// one wave per row: stream 4 planes of S (u8), per-row loss; one global
// write per block (no hot atomics).
__global__ __launch_bounds__(256)
void pass2_mem_kernel(const unsigned char* __restrict__ S,
                      const float* __restrict__ logC,
                      float* __restrict__ rowv) {
  const int tid  = threadIdx.x;
  const int lane = tid & 63;
  const int wid  = tid >> 6;
  const int row  = blockIdx.x * 4 + wid;      // 4096 blocks -> BH rows
  const size_t plane = (size_t)BH * KC;
  const unsigned char* Sr = S + (size_t)row * KC;

  float dp1 = 0.f, dp2 = 0.f, dz1 = 0.f, dz2 = 0.f, nz1 = 0.f, nz2 = 0.f;

  #pragma unroll
  for (int it = 0; it < 2; ++it) {
    const int kb = it * 512 + lane * 8;
    uint2 vz1 = *reinterpret_cast<const uint2*>(Sr + 0 * plane + kb);
    uint2 vz2 = *reinterpret_cast<const uint2*>(Sr + 1 * plane + kb);
    uint2 vp1 = *reinterpret_cast<const uint2*>(Sr + 2 * plane + kb);
    uint2 vp2 = *reinterpret_cast<const uint2*>(Sr + 3 * plane + kb);

    float cz1[8], cz2[8], cp1[8], cp2[8];
    *reinterpret_cast<float4*>(&cz1[0]) = *reinterpret_cast<const float4*>(logC + 0 * KC + kb);
    *reinterpret_cast<float4*>(&cz1[4]) = *reinterpret_cast<const float4*>(logC + 0 * KC + kb + 4);
    *reinterpret_cast<float4*>(&cz2[0]) = *reinterpret_cast<const float4*>(logC + 1 * KC + kb);
    *reinterpret_cast<float4*>(&cz2[4]) = *reinterpret_cast<const float4*>(logC + 1 * KC + kb + 4);
    *reinterpret_cast<float4*>(&cp1[0]) = *reinterpret_cast<const float4*>(logC + 2 * KC + kb);
    *reinterpret_cast<float4*>(&cp1[4]) = *reinterpret_cast<const float4*>(logC + 2 * KC + kb + 4);
    *reinterpret_cast<float4*>(&cp2[0]) = *reinterpret_cast<const float4*>(logC + 3 * KC + kb);
    *reinterpret_cast<float4*>(&cp2[4]) = *reinterpret_cast<const float4*>(logC + 3 * KC + kb + 4);

    unsigned b1[8], b2[8];
    #pragma unroll
    for (int e = 0; e < 4; ++e) {
      b1[e]     = (vp1.x >> (8 * e)) & 0xffu;
      b1[e + 4] = (vp1.y >> (8 * e)) & 0xffu;
      b2[e]     = (vp2.x >> (8 * e)) & 0xffu;
      b2[e + 4] = (vp2.y >> (8 * e)) & 0xffu;
    }
    float tv[8];
    #pragma unroll
    for (int e = 0; e < 8; ++e) {
      float g1 = decG(b1[e], cp1[e]);
      float g2 = decG(b2[e], cp2[e]);
      dp1 += __expf(g1);
      dp2 += __expf(g2);
      tv[e] = g1 + g2;
    }
    #pragma unroll
    for (int e = 0; e < 4; ++e) {
      b1[e]     = (vz1.x >> (8 * e)) & 0xffu;
      b1[e + 4] = (vz1.y >> (8 * e)) & 0xffu;
      b2[e]     = (vz2.x >> (8 * e)) & 0xffu;
      b2[e + 4] = (vz2.y >> (8 * e)) & 0xffu;
    }
    #pragma unroll
    for (int e = 0; e < 8; ++e) {
      float e1 = __expf(decG(b1[e], cz1[e]));
      float e2 = __expf(decG(b2[e], cz2[e]));
      dz1 += e1; nz1 += e1 * tv[e];
      dz2 += e2; nz2 += e2 * tv[e];
    }
  }

  #pragma unroll
  for (int m = 1; m < 64; m <<= 1) {
    dp1 += __shfl_xor(dp1, m); dp2 += __shfl_xor(dp2, m);
    dz1 += __shfl_xor(dz1, m); dz2 += __shfl_xor(dz2, m);
    nz1 += __shfl_xor(nz1, m); nz2 += __shfl_xor(nz2, m);
  }

  __shared__ float red[4];
  if (lane == 0)
    red[wid] = nz1 / dz1 + nz2 / dz2 - 2.0f * (__logf(dp1) + __logf(dp2));
  __syncthreads();
  if (tid == 0)
    rowv[blockIdx.x] = red[0] + red[1] + red[2] + red[3];
}

// 4096 partials -> 16 blocks -> 16 atomics
__global__ void fin_reduce_kernel(const float* __restrict__ rowv,
                                  float* __restrict__ out) {
  int i = blockIdx.x * 256 + threadIdx.x;
  float v = rowv[i];
  #pragma unroll
  for (int m = 1; m < 64; m <<= 1) v += __shfl_xor(v, m);
  __shared__ float ws[4];
  int lane = threadIdx.x & 63, wid = threadIdx.x >> 6;
  if (lane == 0) ws[wid] = v;
  __syncthreads();
  if (threadIdx.x == 0)
    atomicAdd(out, (ws[0] + ws[1] + ws[2] + ws[3]) * (-1.0f / 65536.0f));
}

extern "C" void kernel_launch(void* const* d_in, const int* in_sizes, int n_in,
                              void* d_out, int out_size, void* d_ws, size_t ws_size,
                              hipStream_t stream) {
  const float* z = (const float*)d_in[0];
  const float* p = (const float*)d_in[1];
  const float* c = (const float*)d_in[2];
  char* ws = (char*)d_ws;
  // layout: XA bf16 33.55MB | Cn 0.5MB | colsum 16KB | logC 16KB |
  //         rowv 16KB | S u8 67.1MB
  unsigned short* Xn = (unsigned short*)(ws);
  unsigned short* Cn = (unsigned short*)(ws + 33554432);
  float* colsum = (float*)(ws + 34078720);
  float* logC   = (float*)(ws + 34095104);
  float* rowv   = (float*)(ws + 34111488);
  unsigned char* S = (unsigned char*)(ws + 34127872);
  float* out = (float*)d_out;

  norm_rows_kernel<<<16640, 256, 0, stream>>>(z, p, c, Xn, Cn, colsum, out);
  gemm8_kernel<<<256, 512, 0, stream>>>(Xn, Cn, colsum, S);
  fin_logC_kernel<<<16, 256, 0, stream>>>(colsum, logC);
  pass2_mem_kernel<<<4096, 256, 0, stream>>>(S, logC, rowv);
  fin_reduce_kernel<<<16, 256, 0, stream>>>(rowv, out);
}

// Round 12
// 192.869 us; speedup vs baseline: 1.2676x; 1.2612x over previous
//
#include <hip/hip_runtime.h>
#include <math.h>

#define BH  16384   // half batch
#define B2  32768
#define DIM 256
#define KC  1024    // clusters

typedef __bf16 bf16x8 __attribute__((ext_vector_type(8)));
typedef float  f32x4  __attribute__((ext_vector_type(4)));

__device__ __forceinline__ unsigned short f2bf(float f) {
  unsigned int u = __float_as_uint(f);
  u += 0x7FFFu + ((u >> 16) & 1u);   // RNE; inputs are finite
  return (unsigned short)(u >> 16);
}

__device__ __forceinline__ float vsqrt(float x) {
  float r; asm("v_sqrt_f32 %0, %1" : "=v"(r) : "v"(x)); return r;
}

__device__ __forceinline__ void gld_lds16(const void* g, void* l) {
  __builtin_amdgcn_global_load_lds(
      (const __attribute__((address_space(1))) void*)g,
      (__attribute__((address_space(3))) void*)l, 16, 0, 0);
}

// one wave per row: l2-normalize and convert to bf16.
// Blocks 0..15 also zero colsum; block 16 zeros out.
__global__ void norm_rows_kernel(const float* __restrict__ z,
                                 const float* __restrict__ p,
                                 const float* __restrict__ c,
                                 unsigned short* __restrict__ Xn,
                                 unsigned short* __restrict__ Cn,
                                 float* __restrict__ colsum,
                                 float* __restrict__ out) {
  if (blockIdx.x < 16) colsum[blockIdx.x * 256 + threadIdx.x] = 0.0f;
  if (blockIdx.x == 16 && threadIdx.x == 0) out[0] = 0.0f;

  int wave = threadIdx.x >> 6;
  int lane = threadIdx.x & 63;
  int row  = blockIdx.x * 4 + wave;          // 0 .. 66559
  const float* src; unsigned short* dst; int r;
  if (row < B2)        { src = z; dst = Xn; r = row; }
  else if (row < 2*B2) { src = p; dst = Xn + (size_t)B2 * DIM; r = row - B2; }
  else                 { src = c; dst = Cn; r = row - 2*B2; }
  float4 v = *reinterpret_cast<const float4*>(src + (size_t)r * DIM + lane * 4);
  float ss = v.x*v.x + v.y*v.y + v.z*v.z + v.w*v.w;
  #pragma unroll
  for (int m = 1; m < 64; m <<= 1) ss += __shfl_xor(ss, m);
  float inv = 1.0f / fmaxf(vsqrt(ss), 1e-12f);
  ushort4 o;
  o.x = f2bf(v.x * inv); o.y = f2bf(v.y * inv);
  o.z = f2bf(v.z * inv); o.w = f2bf(v.w * inv);
  *reinterpret_cast<ushort4*>(dst + (size_t)r * DIM + lane * 4) = o;
}

__global__ void fin_logC_kernel(const float* __restrict__ colsum,
                                float* __restrict__ logC) {
  int i = blockIdx.x * 256 + threadIdx.x;
  if (i < 4 * KC) logC[i] = 40.0f + __logf(colsum[i]);
}

// gemm_s (BK=32): S[mat][b][k] = u8 quantized dot; colsum[mat][k] += LUT[e]
// LDS 40KB -> 4 blocks/CU (16 waves) vs r9's 68KB/2 blocks. 32 t-steps under
// #pragma unroll 1 (compact body; all frag indices static). LUT 8-replica.
// NOTE (r10/r11 lesson): 512-thread variants get VGPR-clamped to 128 and
// spill the accumulator regardless of __launch_bounds__ -- stay at 256 thr.
__global__ __launch_bounds__(256, 4)
void gemm_s_kernel(const unsigned short* __restrict__ XA,  // [4][BH][DIM]
                   const unsigned short* __restrict__ Cn,  // [KC][DIM]
                   float* __restrict__ colsum,
                   unsigned char* __restrict__ S) {        // [4][BH][KC] u8
  __shared__ __align__(16) char lds[40960]; // A:0/8192 B:16384/24576 LUT:32768
  float* lut8 = (float*)(lds + 32768);
  const int id  = blockIdx.x;            // 1024
  const int xcd = id & 7, idx = id >> 3;
  const int wk  = xcd * 128 + idx;       // bijective (1024 % 8 == 0)
  const int panel = wk >> 3, col = wk & 7;
  const int tm0 = panel * 128, tn0 = col * 128;

  const int tid  = threadIdx.x;
  const int lane = tid & 63;
  const int wid  = tid >> 6;
  const int wm   = wid >> 1, wn = wid & 1;
  const int l15  = lane & 15, l4 = lane >> 4;
  const int l7   = lane & 7;

  // LUT: 256 entries x 8 replicas (index (e<<3)|l7 -> ~2-way max conflict)
  {
    float d = ((float)tid - 127.5f) * (1.0f / 255.0f);
    float L = 20.0f * vsqrt(2.0f - 2.0f * d);
    float v = __expf(L - 40.0f);
    ((float4*)lut8)[tid * 2]     = (float4){v, v, v, v};
    ((float4*)lut8)[tid * 2 + 1] = (float4){v, v, v, v};
  }

  // staging: tile = 128 rows x 32 K (64 B/row) = 512 slots of 16 B
  int arow[2], acs[2];
  #pragma unroll
  for (int it = 0; it < 2; ++it) {
    int slot = it * 256 + tid;
    arow[it] = slot >> 2;
    acs[it]  = (slot & 3) ^ (arow[it] & 3);   // involution within 64B row
  }
  const char* Abase = (const char*)XA + (size_t)tm0 * 512;
  const char* Bbase = (const char*)Cn + (size_t)tn0 * 512;

  auto stage = [&](int t) {
    const int mat = t >> 3, bk = t & 7, b = t & 1;
    const char* ab = Abase + ((size_t)mat << 23);   // mat * BH * 512
    #pragma unroll
    for (int it = 0; it < 2; ++it) {
      gld_lds16(ab + (size_t)arow[it] * 512 + bk * 64 + acs[it] * 16,
                lds + b * 8192 + (it * 256 + tid) * 16);
      gld_lds16(Bbase + (size_t)arow[it] * 512 + bk * 64 + acs[it] * 16,
                lds + 16384 + b * 8192 + (it * 256 + tid) * 16);
    }
  };

  f32x4 acc[4][4];
  stage(0);
  __syncthreads();

  #pragma unroll 1
  for (int t = 0; t < 32; ++t) {
    if (t < 31) stage(t + 1);
    const int b = t & 1;

    if ((t & 7) == 0) {
      #pragma unroll
      for (int fi = 0; fi < 4; ++fi)
        #pragma unroll
        for (int fj = 0; fj < 4; ++fj)
          acc[fi][fj] = (f32x4){0.f, 0.f, 0.f, 0.f};
    }

    bf16x8 aF[4], bF[4];
    #pragma unroll
    for (int f = 0; f < 4; ++f) {
      const int ra = wm * 64 + f * 16 + l15;
      aF[f] = *reinterpret_cast<const bf16x8*>(
          lds + b * 8192 + ra * 64 + ((l4 ^ (ra & 3)) << 4));
      const int rb = wn * 64 + f * 16 + l15;
      bF[f] = *reinterpret_cast<const bf16x8*>(
          lds + 16384 + b * 8192 + rb * 64 + ((l4 ^ (rb & 3)) << 4));
    }
    #pragma unroll
    for (int fi = 0; fi < 4; ++fi)
      #pragma unroll
      for (int fj = 0; fj < 4; ++fj)
        acc[fi][fj] = __builtin_amdgcn_mfma_f32_16x16x32_bf16(
            aF[fi], bF[fj], acc[fi][fj], 0, 0, 0);

    if ((t & 7) == 7) {
      const int mat = t >> 3;
      unsigned char* Sp = S + ((size_t)mat * BH + tm0) * KC + tn0;
      #pragma unroll
      for (int fj = 0; fj < 4; ++fj) {
        float cp = 0.0f;
        #pragma unroll
        for (int fi = 0; fi < 4; ++fi)
          #pragma unroll
          for (int i = 0; i < 4; ++i) {
            float v = fmaf(acc[fi][fj][i], 255.0f, 128.0f);
            v = fminf(fmaxf(v, 0.0f), 255.0f);
            unsigned e = (unsigned)v;
            cp += lut8[(e << 3) | l7];
            int row  = wm * 64 + fi * 16 + l4 * 4 + i;
            int ccol = wn * 64 + fj * 16 + l15;
            Sp[(size_t)row * KC + ccol] = (unsigned char)e;
          }
        cp += __shfl_xor(cp, 16);
        cp += __shfl_xor(cp, 32);
        if (l4 == 0)
          atomicAdd(&colsum[mat * KC + tn0 + wn * 64 + fj * 16 + l15], cp);
      }
    }
    __syncthreads();
  }
}

// decode u8 -> G = L(d_e) - lc
__device__ __forceinline__ float decG(unsigned e, float lc) {
  float d = fmaf((float)e, 1.0f / 255.0f, -0.5f);
  float L = 20.0f * vsqrt(fmaf(-2.0f, d, 2.0f));
  return L - lc;
}

// one wave per row: stream 4 planes of S (u8); all 8 plane-loads hoisted
// ahead of the transcendental chain; one global write per block.
__global__ __launch_bounds__(256)
void pass2_mem_kernel(const unsigned char* __restrict__ S,
                      const float* __restrict__ logC,
                      float* __restrict__ rowv) {
  const int tid  = threadIdx.x;
  const int lane = tid & 63;
  const int wid  = tid >> 6;
  const int row  = blockIdx.x * 4 + wid;      // 4096 blocks -> BH rows
  const size_t plane = (size_t)BH * KC;
  const unsigned char* Sr = S + (size_t)row * KC + lane * 8;

  // hoist all S loads (both k-halves, 4 planes)
  uint2 vz1a = *reinterpret_cast<const uint2*>(Sr + 0 * plane);
  uint2 vz1b = *reinterpret_cast<const uint2*>(Sr + 0 * plane + 512);
  uint2 vz2a = *reinterpret_cast<const uint2*>(Sr + 1 * plane);
  uint2 vz2b = *reinterpret_cast<const uint2*>(Sr + 1 * plane + 512);
  uint2 vp1a = *reinterpret_cast<const uint2*>(Sr + 2 * plane);
  uint2 vp1b = *reinterpret_cast<const uint2*>(Sr + 2 * plane + 512);
  uint2 vp2a = *reinterpret_cast<const uint2*>(Sr + 3 * plane);
  uint2 vp2b = *reinterpret_cast<const uint2*>(Sr + 3 * plane + 512);

  float dp1 = 0.f, dp2 = 0.f, dz1 = 0.f, dz2 = 0.f, nz1 = 0.f, nz2 = 0.f;

  auto doit = [&](uint2 vz1, uint2 vz2, uint2 vp1, uint2 vp2, int kb) {
    float cz1[8], cz2[8], cp1[8], cp2[8];
    *reinterpret_cast<float4*>(&cz1[0]) = *reinterpret_cast<const float4*>(logC + 0 * KC + kb);
    *reinterpret_cast<float4*>(&cz1[4]) = *reinterpret_cast<const float4*>(logC + 0 * KC + kb + 4);
    *reinterpret_cast<float4*>(&cz2[0]) = *reinterpret_cast<const float4*>(logC + 1 * KC + kb);
    *reinterpret_cast<float4*>(&cz2[4]) = *reinterpret_cast<const float4*>(logC + 1 * KC + kb + 4);
    *reinterpret_cast<float4*>(&cp1[0]) = *reinterpret_cast<const float4*>(logC + 2 * KC + kb);
    *reinterpret_cast<float4*>(&cp1[4]) = *reinterpret_cast<const float4*>(logC + 2 * KC + kb + 4);
    *reinterpret_cast<float4*>(&cp2[0]) = *reinterpret_cast<const float4*>(logC + 3 * KC + kb);
    *reinterpret_cast<float4*>(&cp2[4]) = *reinterpret_cast<const float4*>(logC + 3 * KC + kb + 4);

    unsigned b1[8], b2[8];
    #pragma unroll
    for (int e = 0; e < 4; ++e) {
      b1[e]     = (vp1.x >> (8 * e)) & 0xffu;
      b1[e + 4] = (vp1.y >> (8 * e)) & 0xffu;
      b2[e]     = (vp2.x >> (8 * e)) & 0xffu;
      b2[e + 4] = (vp2.y >> (8 * e)) & 0xffu;
    }
    float tv[8];
    #pragma unroll
    for (int e = 0; e < 8; ++e) {
      float g1 = decG(b1[e], cp1[e]);
      float g2 = decG(b2[e], cp2[e]);
      dp1 += __expf(g1);
      dp2 += __expf(g2);
      tv[e] = g1 + g2;
    }
    #pragma unroll
    for (int e = 0; e < 4; ++e) {
      b1[e]     = (vz1.x >> (8 * e)) & 0xffu;
      b1[e + 4] = (vz1.y >> (8 * e)) & 0xffu;
      b2[e]     = (vz2.x >> (8 * e)) & 0xffu;
      b2[e + 4] = (vz2.y >> (8 * e)) & 0xffu;
    }
    #pragma unroll
    for (int e = 0; e < 8; ++e) {
      float e1 = __expf(decG(b1[e], cz1[e]));
      float e2 = __expf(decG(b2[e], cz2[e]));
      dz1 += e1; nz1 += e1 * tv[e];
      dz2 += e2; nz2 += e2 * tv[e];
    }
  };

  doit(vz1a, vz2a, vp1a, vp2a, lane * 8);
  doit(vz1b, vz2b, vp1b, vp2b, 512 + lane * 8);

  #pragma unroll
  for (int m = 1; m < 64; m <<= 1) {
    dp1 += __shfl_xor(dp1, m); dp2 += __shfl_xor(dp2, m);
    dz1 += __shfl_xor(dz1, m); dz2 += __shfl_xor(dz2, m);
    nz1 += __shfl_xor(nz1, m); nz2 += __shfl_xor(nz2, m);
  }

  __shared__ float red[4];
  if (lane == 0)
    red[wid] = nz1 / dz1 + nz2 / dz2 - 2.0f * (__logf(dp1) + __logf(dp2));
  __syncthreads();
  if (tid == 0)
    rowv[blockIdx.x] = red[0] + red[1] + red[2] + red[3];
}

// 4096 partials -> 16 blocks -> 16 atomics
__global__ void fin_reduce_kernel(const float* __restrict__ rowv,
                                  float* __restrict__ out) {
  int i = blockIdx.x * 256 + threadIdx.x;
  float v = rowv[i];
  #pragma unroll
  for (int m = 1; m < 64; m <<= 1) v += __shfl_xor(v, m);
  __shared__ float ws[4];
  int lane = threadIdx.x & 63, wid = threadIdx.x >> 6;
  if (lane == 0) ws[wid] = v;
  __syncthreads();
  if (threadIdx.x == 0)
    atomicAdd(out, (ws[0] + ws[1] + ws[2] + ws[3]) * (-1.0f / 65536.0f));
}

extern "C" void kernel_launch(void* const* d_in, const int* in_sizes, int n_in,
                              void* d_out, int out_size, void* d_ws, size_t ws_size,
                              hipStream_t stream) {
  const float* z = (const float*)d_in[0];
  const float* p = (const float*)d_in[1];
  const float* c = (const float*)d_in[2];
  char* ws = (char*)d_ws;
  // layout: XA bf16 33.55MB | Cn 0.5MB | colsum 16KB | logC 16KB |
  //         rowv 16KB | S u8 67.1MB
  unsigned short* Xn = (unsigned short*)(ws);
  unsigned short* Cn = (unsigned short*)(ws + 33554432);
  float* colsum = (float*)(ws + 34078720);
  float* logC   = (float*)(ws + 34095104);
  float* rowv   = (float*)(ws + 34111488);
  unsigned char* S = (unsigned char*)(ws + 34127872);
  float* out = (float*)d_out;

  norm_rows_kernel<<<16640, 256, 0, stream>>>(z, p, c, Xn, Cn, colsum, out);
  gemm_s_kernel<<<1024, 256, 0, stream>>>(Xn, Cn, colsum, S);
  fin_logC_kernel<<<16, 256, 0, stream>>>(colsum, logC);
  pass2_mem_kernel<<<4096, 256, 0, stream>>>(S, logC, rowv);
  fin_reduce_kernel<<<16, 256, 0, stream>>>(rowv, out);
}

// Round 13
// 132.058 us; speedup vs baseline: 1.8514x; 1.4605x over previous
//
#include <hip/hip_runtime.h>
#include <math.h>

#define BH  16384   // half batch
#define B2  32768
#define DIM 256
#define KC  1024    // clusters

typedef __bf16 bf16x8 __attribute__((ext_vector_type(8)));
typedef float  f32x4  __attribute__((ext_vector_type(4)));

__device__ __forceinline__ unsigned short f2bf(float f) {
  unsigned int u = __float_as_uint(f);
  u += 0x7FFFu + ((u >> 16) & 1u);   // RNE; inputs are finite
  return (unsigned short)(u >> 16);
}

__device__ __forceinline__ float vsqrt(float x) {
  float r; asm("v_sqrt_f32 %0, %1" : "=v"(r) : "v"(x)); return r;
}

__device__ __forceinline__ void gld_lds16(const void* g, void* l) {
  __builtin_amdgcn_global_load_lds(
      (const __attribute__((address_space(1))) void*)g,
      (__attribute__((address_space(3))) void*)l, 16, 0, 0);
}

// one wave per row: l2-normalize and convert to bf16.
// Blocks 0..15 also zero colsum; block 16 zeros out.
__global__ void norm_rows_kernel(const float* __restrict__ z,
                                 const float* __restrict__ p,
                                 const float* __restrict__ c,
                                 unsigned short* __restrict__ Xn,
                                 unsigned short* __restrict__ Cn,
                                 float* __restrict__ colsum,
                                 float* __restrict__ out) {
  if (blockIdx.x < 16) colsum[blockIdx.x * 256 + threadIdx.x] = 0.0f;
  if (blockIdx.x == 16 && threadIdx.x == 0) out[0] = 0.0f;

  int wave = threadIdx.x >> 6;
  int lane = threadIdx.x & 63;
  int row  = blockIdx.x * 4 + wave;          // 0 .. 66559
  const float* src; unsigned short* dst; int r;
  if (row < B2)        { src = z; dst = Xn; r = row; }
  else if (row < 2*B2) { src = p; dst = Xn + (size_t)B2 * DIM; r = row - B2; }
  else                 { src = c; dst = Cn; r = row - 2*B2; }
  float4 v = *reinterpret_cast<const float4*>(src + (size_t)r * DIM + lane * 4);
  float ss = v.x*v.x + v.y*v.y + v.z*v.z + v.w*v.w;
  #pragma unroll
  for (int m = 1; m < 64; m <<= 1) ss += __shfl_xor(ss, m);
  float inv = 1.0f / fmaxf(vsqrt(ss), 1e-12f);
  ushort4 o;
  o.x = f2bf(v.x * inv); o.y = f2bf(v.y * inv);
  o.z = f2bf(v.z * inv); o.w = f2bf(v.w * inv);
  *reinterpret_cast<ushort4*>(dst + (size_t)r * DIM + lane * 4) = o;
}

__global__ void fin_logC_kernel(const float* __restrict__ colsum,
                                float* __restrict__ logC) {
  int i = blockIdx.x * 256 + threadIdx.x;
  if (i < 4 * KC) logC[i] = 40.0f + __logf(colsum[i]);
}

// gemm_s: S[mat][b][k] = u8 quantized dot; colsum[mat][k] += LUT[e]
// r9 structure EXACTLY (BK=64, 256 thr, launch_bounds(256,2) -> ~120 VGPR,
// no spill) with ONE change: counted-vmcnt raw-barrier pipeline (T4) instead
// of __syncthreads(), fully unrolled so all indices stay compile-time.
// r10/r11/r12 lesson: any config capping regs <160 spills acc -> 2-3x loss.
__global__ __launch_bounds__(256, 2)
void gemm_s_kernel(const unsigned short* __restrict__ XA,  // [4][BH][DIM]
                   const unsigned short* __restrict__ Cn,  // [KC][DIM]
                   float* __restrict__ colsum,
                   unsigned char* __restrict__ S) {        // [4][BH][KC] u8
  __shared__ __align__(16) char lds[65536 + 4096];  // tiles + 256x4 f32 LUT
  float* lut4 = (float*)(lds + 65536);
  const int id  = blockIdx.x;            // 1024
  const int xcd = id & 7, idx = id >> 3;
  const int wk  = xcd * 128 + idx;       // bijective (1024 % 8 == 0)
  const int panel = wk >> 3, col = wk & 7;
  const int tm0 = panel * 128, tn0 = col * 128;

  const int tid  = threadIdx.x;
  const int lane = tid & 63;
  const int wid  = tid >> 6;
  const int wm   = wid >> 1, wn = wid & 1;
  const int l15  = lane & 15, l4 = lane >> 4;
  const int slot = tid & 3;

  int arow[4], acs[4];
  #pragma unroll
  for (int it = 0; it < 4; ++it) {
    int sl = it * 256 + tid;
    int r = sl >> 3, c = sl & 7;
    arow[it] = r;
    acs[it]  = c ^ (r & 7);    // pre-swizzled source chunk (involution)
  }
  const char* Abase = (const char*)XA + (size_t)tm0 * 512;
  const char* Bbase = (const char*)Cn + (size_t)tn0 * 512;

  auto stage = [&](int t) {
    const int mat = t >> 2;
    const int bk  = t & 3;
    const int b   = t & 1;
    const char* ab = Abase + ((size_t)mat << 23);   // mat * BH * 512
    #pragma unroll
    for (int it = 0; it < 4; ++it) {
      gld_lds16(ab + (size_t)arow[it] * 512 + bk * 128 + acs[it] * 16,
                lds + b * 16384 + (it * 256 + tid) * 16);
      gld_lds16(Bbase + (size_t)arow[it] * 512 + bk * 128 + acs[it] * 16,
                lds + 32768 + b * 16384 + (it * 256 + tid) * 16);
    }
  };

  // build LUT (published by the initial __syncthreads below)
  if (tid < 256) {
    float d = ((float)tid - 127.5f) * (1.0f / 255.0f);
    float L = 20.0f * vsqrt(2.0f - 2.0f * d);
    float v = __expf(L - 40.0f);
    ((float4*)lut4)[tid] = (float4){v, v, v, v};
  }

  f32x4 acc[4][4];
  stage(0);
  __syncthreads();   // once: drains stage(0), publishes LUT

  #pragma unroll
  for (int t = 0; t < 16; ++t) {
    // T4: issue next stage, then wait only until stage(t) is complete,
    // leaving stage(t+1)'s 8 loads in flight across both barriers.
    if (t < 15) {
      stage(t + 1);
      asm volatile("s_waitcnt vmcnt(8)" ::: "memory");
    } else {
      asm volatile("s_waitcnt vmcnt(0)" ::: "memory");
    }
    __builtin_amdgcn_sched_barrier(0);
    __builtin_amdgcn_s_barrier();       // all waves' stage(t) now in LDS
    __builtin_amdgcn_sched_barrier(0);

    const int b  = t & 1;
    const int mat = t >> 2, bk = t & 3;

    if (bk == 0) {
      #pragma unroll
      for (int fi = 0; fi < 4; ++fi)
        #pragma unroll
        for (int fj = 0; fj < 4; ++fj)
          acc[fi][fj] = (f32x4){0.f, 0.f, 0.f, 0.f};
    }

    #pragma unroll
    for (int kc = 0; kc < 2; ++kc) {
      bf16x8 aF[4], bF[4];
      #pragma unroll
      for (int f = 0; f < 4; ++f) {
        const int ra = wm * 64 + f * 16 + l15;
        aF[f] = *reinterpret_cast<const bf16x8*>(
            lds + b * 16384 + ra * 128 + ((((kc << 2) | l4) ^ (ra & 7)) << 4));
        const int rb = wn * 64 + f * 16 + l15;
        bF[f] = *reinterpret_cast<const bf16x8*>(
            lds + 32768 + b * 16384 + rb * 128 + ((((kc << 2) | l4) ^ (rb & 7)) << 4));
      }
      #pragma unroll
      for (int fi = 0; fi < 4; ++fi)
        #pragma unroll
        for (int fj = 0; fj < 4; ++fj)
          acc[fi][fj] = __builtin_amdgcn_mfma_f32_16x16x32_bf16(
              aF[fi], bF[fj], acc[fi][fj], 0, 0, 0);
    }

    if (bk == 3) {
      unsigned char* Sp = S + ((size_t)mat * BH + tm0) * KC + tn0;
      #pragma unroll
      for (int fj = 0; fj < 4; ++fj) {
        float cp = 0.0f;
        #pragma unroll
        for (int fi = 0; fi < 4; ++fi)
          #pragma unroll
          for (int i = 0; i < 4; ++i) {
            float v = fmaf(acc[fi][fj][i], 255.0f, 128.0f);
            v = fminf(fmaxf(v, 0.0f), 255.0f);
            unsigned e = (unsigned)v;
            cp += lut4[(e << 2) | slot];
            int row  = wm * 64 + fi * 16 + l4 * 4 + i;
            int ccol = wn * 64 + fj * 16 + l15;
            Sp[(size_t)row * KC + ccol] = (unsigned char)e;
          }
        cp += __shfl_xor(cp, 16);
        cp += __shfl_xor(cp, 32);
        if (l4 == 0)
          atomicAdd(&colsum[mat * KC + tn0 + wn * 64 + fj * 16 + l15], cp);
      }
    }

    if (t < 15) {
      __builtin_amdgcn_sched_barrier(0);
      __builtin_amdgcn_s_barrier();     // buf b fully read before restage
      __builtin_amdgcn_sched_barrier(0);
    }
  }
}

// decode u8 -> G = L(d_e) - lc
__device__ __forceinline__ float decG(unsigned e, float lc) {
  float d = fmaf((float)e, 1.0f / 255.0f, -0.5f);
  float L = 20.0f * vsqrt(fmaf(-2.0f, d, 2.0f));
  return L - lc;
}

// one wave per row: stream 4 planes of S (u8); all 8 plane-loads hoisted
// ahead of the transcendental chain; one global write per block.
__global__ __launch_bounds__(256)
void pass2_mem_kernel(const unsigned char* __restrict__ S,
                      const float* __restrict__ logC,
                      float* __restrict__ rowv) {
  const int tid  = threadIdx.x;
  const int lane = tid & 63;
  const int wid  = tid >> 6;
  const int row  = blockIdx.x * 4 + wid;      // 4096 blocks -> BH rows
  const size_t plane = (size_t)BH * KC;
  const unsigned char* Sr = S + (size_t)row * KC + lane * 8;

  // hoist all S loads (both k-halves, 4 planes)
  uint2 vz1a = *reinterpret_cast<const uint2*>(Sr + 0 * plane);
  uint2 vz1b = *reinterpret_cast<const uint2*>(Sr + 0 * plane + 512);
  uint2 vz2a = *reinterpret_cast<const uint2*>(Sr + 1 * plane);
  uint2 vz2b = *reinterpret_cast<const uint2*>(Sr + 1 * plane + 512);
  uint2 vp1a = *reinterpret_cast<const uint2*>(Sr + 2 * plane);
  uint2 vp1b = *reinterpret_cast<const uint2*>(Sr + 2 * plane + 512);
  uint2 vp2a = *reinterpret_cast<const uint2*>(Sr + 3 * plane);
  uint2 vp2b = *reinterpret_cast<const uint2*>(Sr + 3 * plane + 512);

  float dp1 = 0.f, dp2 = 0.f, dz1 = 0.f, dz2 = 0.f, nz1 = 0.f, nz2 = 0.f;

  auto doit = [&](uint2 vz1, uint2 vz2, uint2 vp1, uint2 vp2, int kb) {
    float cz1[8], cz2[8], cp1[8], cp2[8];
    *reinterpret_cast<float4*>(&cz1[0]) = *reinterpret_cast<const float4*>(logC + 0 * KC + kb);
    *reinterpret_cast<float4*>(&cz1[4]) = *reinterpret_cast<const float4*>(logC + 0 * KC + kb + 4);
    *reinterpret_cast<float4*>(&cz2[0]) = *reinterpret_cast<const float4*>(logC + 1 * KC + kb);
    *reinterpret_cast<float4*>(&cz2[4]) = *reinterpret_cast<const float4*>(logC + 1 * KC + kb + 4);
    *reinterpret_cast<float4*>(&cp1[0]) = *reinterpret_cast<const float4*>(logC + 2 * KC + kb);
    *reinterpret_cast<float4*>(&cp1[4]) = *reinterpret_cast<const float4*>(logC + 2 * KC + kb + 4);
    *reinterpret_cast<float4*>(&cp2[0]) = *reinterpret_cast<const float4*>(logC + 3 * KC + kb);
    *reinterpret_cast<float4*>(&cp2[4]) = *reinterpret_cast<const float4*>(logC + 3 * KC + kb + 4);

    unsigned b1[8], b2[8];
    #pragma unroll
    for (int e = 0; e < 4; ++e) {
      b1[e]     = (vp1.x >> (8 * e)) & 0xffu;
      b1[e + 4] = (vp1.y >> (8 * e)) & 0xffu;
      b2[e]     = (vp2.x >> (8 * e)) & 0xffu;
      b2[e + 4] = (vp2.y >> (8 * e)) & 0xffu;
    }
    float tv[8];
    #pragma unroll
    for (int e = 0; e < 8; ++e) {
      float g1 = decG(b1[e], cp1[e]);
      float g2 = decG(b2[e], cp2[e]);
      dp1 += __expf(g1);
      dp2 += __expf(g2);
      tv[e] = g1 + g2;
    }
    #pragma unroll
    for (int e = 0; e < 4; ++e) {
      b1[e]     = (vz1.x >> (8 * e)) & 0xffu;
      b1[e + 4] = (vz1.y >> (8 * e)) & 0xffu;
      b2[e]     = (vz2.x >> (8 * e)) & 0xffu;
      b2[e + 4] = (vz2.y >> (8 * e)) & 0xffu;
    }
    #pragma unroll
    for (int e = 0; e < 8; ++e) {
      float e1 = __expf(decG(b1[e], cz1[e]));
      float e2 = __expf(decG(b2[e], cz2[e]));
      dz1 += e1; nz1 += e1 * tv[e];
      dz2 += e2; nz2 += e2 * tv[e];
    }
  };

  doit(vz1a, vz2a, vp1a, vp2a, lane * 8);
  doit(vz1b, vz2b, vp1b, vp2b, 512 + lane * 8);

  #pragma unroll
  for (int m = 1; m < 64; m <<= 1) {
    dp1 += __shfl_xor(dp1, m); dp2 += __shfl_xor(dp2, m);
    dz1 += __shfl_xor(dz1, m); dz2 += __shfl_xor(dz2, m);
    nz1 += __shfl_xor(nz1, m); nz2 += __shfl_xor(nz2, m);
  }

  __shared__ float red[4];
  if (lane == 0)
    red[wid] = nz1 / dz1 + nz2 / dz2 - 2.0f * (__logf(dp1) + __logf(dp2));
  __syncthreads();
  if (tid == 0)
    rowv[blockIdx.x] = red[0] + red[1] + red[2] + red[3];
}

// 4096 partials -> 16 blocks -> 16 atomics
__global__ void fin_reduce_kernel(const float* __restrict__ rowv,
                                  float* __restrict__ out) {
  int i = blockIdx.x * 256 + threadIdx.x;
  float v = rowv[i];
  #pragma unroll
  for (int m = 1; m < 64; m <<= 1) v += __shfl_xor(v, m);
  __shared__ float ws[4];
  int lane = threadIdx.x & 63, wid = threadIdx.x >> 6;
  if (lane == 0) ws[wid] = v;
  __syncthreads();
  if (threadIdx.x == 0)
    atomicAdd(out, (ws[0] + ws[1] + ws[2] + ws[3]) * (-1.0f / 65536.0f));
}

extern "C" void kernel_launch(void* const* d_in, const int* in_sizes, int n_in,
                              void* d_out, int out_size, void* d_ws, size_t ws_size,
                              hipStream_t stream) {
  const float* z = (const float*)d_in[0];
  const float* p = (const float*)d_in[1];
  const float* c = (const float*)d_in[2];
  char* ws = (char*)d_ws;
  // layout: XA bf16 33.55MB | Cn 0.5MB | colsum 16KB | logC 16KB |
  //         rowv 16KB | S u8 67.1MB
  unsigned short* Xn = (unsigned short*)(ws);
  unsigned short* Cn = (unsigned short*)(ws + 33554432);
  float* colsum = (float*)(ws + 34078720);
  float* logC   = (float*)(ws + 34095104);
  float* rowv   = (float*)(ws + 34111488);
  unsigned char* S = (unsigned char*)(ws + 34127872);
  float* out = (float*)d_out;

  norm_rows_kernel<<<16640, 256, 0, stream>>>(z, p, c, Xn, Cn, colsum, out);
  gemm_s_kernel<<<1024, 256, 0, stream>>>(Xn, Cn, colsum, S);
  fin_logC_kernel<<<16, 256, 0, stream>>>(colsum, logC);
  pass2_mem_kernel<<<4096, 256, 0, stream>>>(S, logC, rowv);
  fin_reduce_kernel<<<16, 256, 0, stream>>>(rowv, out);
}

// Round 14
// 107.714 us; speedup vs baseline: 2.2698x; 1.2260x over previous
//
#include <hip/hip_runtime.h>
#include <math.h>

#define BH  16384   // half batch
#define B2  32768
#define DIM 256
#define KC  1024    // clusters

typedef __bf16 bf16x8 __attribute__((ext_vector_type(8)));
typedef float  f32x4  __attribute__((ext_vector_type(4)));

__device__ __forceinline__ unsigned short f2bf(float f) {
  unsigned int u = __float_as_uint(f);
  u += 0x7FFFu + ((u >> 16) & 1u);   // RNE; inputs are finite
  return (unsigned short)(u >> 16);
}

__device__ __forceinline__ float vsqrt(float x) {
  float r; asm("v_sqrt_f32 %0, %1" : "=v"(r) : "v"(x)); return r;
}

__device__ __forceinline__ void gld_lds16(const void* g, void* l) {
  __builtin_amdgcn_global_load_lds(
      (const __attribute__((address_space(1))) void*)g,
      (__attribute__((address_space(3))) void*)l, 16, 0, 0);
}

// one wave per row: l2-normalize and convert to bf16.
// Blocks 0..15 also zero colsum; block 16 zeros out.
__global__ void norm_rows_kernel(const float* __restrict__ z,
                                 const float* __restrict__ p,
                                 const float* __restrict__ c,
                                 unsigned short* __restrict__ Xn,
                                 unsigned short* __restrict__ Cn,
                                 float* __restrict__ colsum,
                                 float* __restrict__ out) {
  if (blockIdx.x < 16) colsum[blockIdx.x * 256 + threadIdx.x] = 0.0f;
  if (blockIdx.x == 16 && threadIdx.x == 0) out[0] = 0.0f;

  int wave = threadIdx.x >> 6;
  int lane = threadIdx.x & 63;
  int row  = blockIdx.x * 4 + wave;          // 0 .. 66559
  const float* src; unsigned short* dst; int r;
  if (row < B2)        { src = z; dst = Xn; r = row; }
  else if (row < 2*B2) { src = p; dst = Xn + (size_t)B2 * DIM; r = row - B2; }
  else                 { src = c; dst = Cn; r = row - 2*B2; }
  float4 v = *reinterpret_cast<const float4*>(src + (size_t)r * DIM + lane * 4);
  float ss = v.x*v.x + v.y*v.y + v.z*v.z + v.w*v.w;
  #pragma unroll
  for (int m = 1; m < 64; m <<= 1) ss += __shfl_xor(ss, m);
  float inv = 1.0f / fmaxf(vsqrt(ss), 1e-12f);
  ushort4 o;
  o.x = f2bf(v.x * inv); o.y = f2bf(v.y * inv);
  o.z = f2bf(v.z * inv); o.w = f2bf(v.w * inv);
  *reinterpret_cast<ushort4*>(dst + (size_t)r * DIM + lane * 4) = o;
}

__global__ void fin_logC_kernel(const float* __restrict__ colsum,
                                float* __restrict__ logC) {
  int i = blockIdx.x * 256 + threadIdx.x;
  if (i < 4 * KC) logC[i] = 40.0f + __logf(colsum[i]);
}

// gemm_s: S[mat][b][k] = u8 quantized dot; colsum[mat][k] += LUT[e]
// r9-EXACT structure (BK=64, 256 thr, launch_bounds(256,2), __syncthreads
// double-buffer, VGPR ~120, no spill). r10-r13 lesson, 4x replicated: any
// variant needing >128 regs or fencing the scheduler (sched_barrier + asm
// waitcnt) hits the 128-VGPR clamp and spills acc -> 1.5-3x regression.
// Counted-vmcnt lever is CLOSED in this toolchain (m139/m141 null confirmed).
__global__ __launch_bounds__(256, 2)
void gemm_s_kernel(const unsigned short* __restrict__ XA,  // [4][BH][DIM]
                   const unsigned short* __restrict__ Cn,  // [KC][DIM]
                   float* __restrict__ colsum,
                   unsigned char* __restrict__ S) {        // [4][BH][KC] u8
  __shared__ __align__(16) char lds[65536 + 4096];  // tiles + 256x4 f32 LUT
  float* lut4 = (float*)(lds + 65536);
  const int id  = blockIdx.x;            // 1024
  const int xcd = id & 7, idx = id >> 3;
  const int wk  = xcd * 128 + idx;       // bijective (1024 % 8 == 0)
  const int panel = wk >> 3, col = wk & 7;
  const int tm0 = panel * 128, tn0 = col * 128;

  const int tid  = threadIdx.x;
  const int lane = tid & 63;
  const int wid  = tid >> 6;
  const int wm   = wid >> 1, wn = wid & 1;
  const int l15  = lane & 15, l4 = lane >> 4;
  const int slot = tid & 3;

  int arow[4], acs[4];
  #pragma unroll
  for (int it = 0; it < 4; ++it) {
    int sl = it * 256 + tid;
    int r = sl >> 3, c = sl & 7;
    arow[it] = r;
    acs[it]  = c ^ (r & 7);    // pre-swizzled source chunk (involution)
  }
  const char* Abase = (const char*)XA + (size_t)tm0 * 512;
  const char* Bbase = (const char*)Cn + (size_t)tn0 * 512;

  auto stage = [&](int t) {
    const int mat = t >> 2;
    const int bk  = t & 3;
    const int b   = t & 1;
    const char* ab = Abase + ((size_t)mat << 23);   // mat * BH * 512
    #pragma unroll
    for (int it = 0; it < 4; ++it) {
      gld_lds16(ab + (size_t)arow[it] * 512 + bk * 128 + acs[it] * 16,
                lds + b * 16384 + (it * 256 + tid) * 16);
      gld_lds16(Bbase + (size_t)arow[it] * 512 + bk * 128 + acs[it] * 16,
                lds + 32768 + b * 16384 + (it * 256 + tid) * 16);
    }
  };

  // build LUT (before the barrier that precedes first compute)
  if (tid < 256) {
    float d = ((float)tid - 127.5f) * (1.0f / 255.0f);
    float L = 20.0f * vsqrt(2.0f - 2.0f * d);
    float v = __expf(L - 40.0f);
    ((float4*)lut4)[tid] = (float4){v, v, v, v};
  }

  f32x4 acc[4][4];
  stage(0);
  __syncthreads();

  for (int t = 0; t < 16; ++t) {
    if (t < 15) stage(t + 1);
    const int b  = t & 1;
    const int mat = t >> 2, bk = t & 3;

    if (bk == 0) {
      #pragma unroll
      for (int fi = 0; fi < 4; ++fi)
        #pragma unroll
        for (int fj = 0; fj < 4; ++fj)
          acc[fi][fj] = (f32x4){0.f, 0.f, 0.f, 0.f};
    }

    #pragma unroll
    for (int kc = 0; kc < 2; ++kc) {
      bf16x8 aF[4], bF[4];
      #pragma unroll
      for (int f = 0; f < 4; ++f) {
        const int ra = wm * 64 + f * 16 + l15;
        aF[f] = *reinterpret_cast<const bf16x8*>(
            lds + b * 16384 + ra * 128 + ((((kc << 2) | l4) ^ (ra & 7)) << 4));
        const int rb = wn * 64 + f * 16 + l15;
        bF[f] = *reinterpret_cast<const bf16x8*>(
            lds + 32768 + b * 16384 + rb * 128 + ((((kc << 2) | l4) ^ (rb & 7)) << 4));
      }
      #pragma unroll
      for (int fi = 0; fi < 4; ++fi)
        #pragma unroll
        for (int fj = 0; fj < 4; ++fj)
          acc[fi][fj] = __builtin_amdgcn_mfma_f32_16x16x32_bf16(
              aF[fi], bF[fj], acc[fi][fj], 0, 0, 0);
    }

    if (bk == 3) {
      unsigned char* Sp = S + ((size_t)mat * BH + tm0) * KC + tn0;
      #pragma unroll
      for (int fj = 0; fj < 4; ++fj) {
        float cp = 0.0f;
        #pragma unroll
        for (int fi = 0; fi < 4; ++fi)
          #pragma unroll
          for (int i = 0; i < 4; ++i) {
            float v = fmaf(acc[fi][fj][i], 255.0f, 128.0f);
            v = fminf(fmaxf(v, 0.0f), 255.0f);
            unsigned e = (unsigned)v;
            cp += lut4[(e << 2) | slot];
            int row  = wm * 64 + fi * 16 + l4 * 4 + i;
            int ccol = wn * 64 + fj * 16 + l15;
            Sp[(size_t)row * KC + ccol] = (unsigned char)e;
          }
        cp += __shfl_xor(cp, 16);
        cp += __shfl_xor(cp, 32);
        if (l4 == 0)
          atomicAdd(&colsum[mat * KC + tn0 + wn * 64 + fj * 16 + l15], cp);
      }
    }
    __syncthreads();
  }
}

// decode u8 -> G = L(d_e) - lc
__device__ __forceinline__ float decG(unsigned e, float lc) {
  float d = fmaf((float)e, 1.0f / 255.0f, -0.5f);
  float L = 20.0f * vsqrt(fmaf(-2.0f, d, 2.0f));
  return L - lc;
}

// one wave per row: stream 4 planes of S (u8); all 8 plane-loads hoisted
// ahead of the transcendental chain; one global write per block.
__global__ __launch_bounds__(256)
void pass2_mem_kernel(const unsigned char* __restrict__ S,
                      const float* __restrict__ logC,
                      float* __restrict__ rowv) {
  const int tid  = threadIdx.x;
  const int lane = tid & 63;
  const int wid  = tid >> 6;
  const int row  = blockIdx.x * 4 + wid;      // 4096 blocks -> BH rows
  const size_t plane = (size_t)BH * KC;
  const unsigned char* Sr = S + (size_t)row * KC + lane * 8;

  // hoist all S loads (both k-halves, 4 planes)
  uint2 vz1a = *reinterpret_cast<const uint2*>(Sr + 0 * plane);
  uint2 vz1b = *reinterpret_cast<const uint2*>(Sr + 0 * plane + 512);
  uint2 vz2a = *reinterpret_cast<const uint2*>(Sr + 1 * plane);
  uint2 vz2b = *reinterpret_cast<const uint2*>(Sr + 1 * plane + 512);
  uint2 vp1a = *reinterpret_cast<const uint2*>(Sr + 2 * plane);
  uint2 vp1b = *reinterpret_cast<const uint2*>(Sr + 2 * plane + 512);
  uint2 vp2a = *reinterpret_cast<const uint2*>(Sr + 3 * plane);
  uint2 vp2b = *reinterpret_cast<const uint2*>(Sr + 3 * plane + 512);

  float dp1 = 0.f, dp2 = 0.f, dz1 = 0.f, dz2 = 0.f, nz1 = 0.f, nz2 = 0.f;

  auto doit = [&](uint2 vz1, uint2 vz2, uint2 vp1, uint2 vp2, int kb) {
    float cz1[8], cz2[8], cp1[8], cp2[8];
    *reinterpret_cast<float4*>(&cz1[0]) = *reinterpret_cast<const float4*>(logC + 0 * KC + kb);
    *reinterpret_cast<float4*>(&cz1[4]) = *reinterpret_cast<const float4*>(logC + 0 * KC + kb + 4);
    *reinterpret_cast<float4*>(&cz2[0]) = *reinterpret_cast<const float4*>(logC + 1 * KC + kb);
    *reinterpret_cast<float4*>(&cz2[4]) = *reinterpret_cast<const float4*>(logC + 1 * KC + kb + 4);
    *reinterpret_cast<float4*>(&cp1[0]) = *reinterpret_cast<const float4*>(logC + 2 * KC + kb);
    *reinterpret_cast<float4*>(&cp1[4]) = *reinterpret_cast<const float4*>(logC + 2 * KC + kb + 4);
    *reinterpret_cast<float4*>(&cp2[0]) = *reinterpret_cast<const float4*>(logC + 3 * KC + kb);
    *reinterpret_cast<float4*>(&cp2[4]) = *reinterpret_cast<const float4*>(logC + 3 * KC + kb + 4);

    unsigned b1[8], b2[8];
    #pragma unroll
    for (int e = 0; e < 4; ++e) {
      b1[e]     = (vp1.x >> (8 * e)) & 0xffu;
      b1[e + 4] = (vp1.y >> (8 * e)) & 0xffu;
      b2[e]     = (vp2.x >> (8 * e)) & 0xffu;
      b2[e + 4] = (vp2.y >> (8 * e)) & 0xffu;
    }
    float tv[8];
    #pragma unroll
    for (int e = 0; e < 8; ++e) {
      float g1 = decG(b1[e], cp1[e]);
      float g2 = decG(b2[e], cp2[e]);
      dp1 += __expf(g1);
      dp2 += __expf(g2);
      tv[e] = g1 + g2;
    }
    #pragma unroll
    for (int e = 0; e < 4; ++e) {
      b1[e]     = (vz1.x >> (8 * e)) & 0xffu;
      b1[e + 4] = (vz1.y >> (8 * e)) & 0xffu;
      b2[e]     = (vz2.x >> (8 * e)) & 0xffu;
      b2[e + 4] = (vz2.y >> (8 * e)) & 0xffu;
    }
    #pragma unroll
    for (int e = 0; e < 8; ++e) {
      float e1 = __expf(decG(b1[e], cz1[e]));
      float e2 = __expf(decG(b2[e], cz2[e]));
      dz1 += e1; nz1 += e1 * tv[e];
      dz2 += e2; nz2 += e2 * tv[e];
    }
  };

  doit(vz1a, vz2a, vp1a, vp2a, lane * 8);
  doit(vz1b, vz2b, vp1b, vp2b, 512 + lane * 8);

  #pragma unroll
  for (int m = 1; m < 64; m <<= 1) {
    dp1 += __shfl_xor(dp1, m); dp2 += __shfl_xor(dp2, m);
    dz1 += __shfl_xor(dz1, m); dz2 += __shfl_xor(dz2, m);
    nz1 += __shfl_xor(nz1, m); nz2 += __shfl_xor(nz2, m);
  }

  __shared__ float red[4];
  if (lane == 0)
    red[wid] = nz1 / dz1 + nz2 / dz2 - 2.0f * (__logf(dp1) + __logf(dp2));
  __syncthreads();
  if (tid == 0)
    rowv[blockIdx.x] = red[0] + red[1] + red[2] + red[3];
}

// 4096 partials -> 16 blocks -> 16 atomics
__global__ void fin_reduce_kernel(const float* __restrict__ rowv,
                                  float* __restrict__ out) {
  int i = blockIdx.x * 256 + threadIdx.x;
  float v = rowv[i];
  #pragma unroll
  for (int m = 1; m < 64; m <<= 1) v += __shfl_xor(v, m);
  __shared__ float ws[4];
  int lane = threadIdx.x & 63, wid = threadIdx.x >> 6;
  if (lane == 0) ws[wid] = v;
  __syncthreads();
  if (threadIdx.x == 0)
    atomicAdd(out, (ws[0] + ws[1] + ws[2] + ws[3]) * (-1.0f / 65536.0f));
}

extern "C" void kernel_launch(void* const* d_in, const int* in_sizes, int n_in,
                              void* d_out, int out_size, void* d_ws, size_t ws_size,
                              hipStream_t stream) {
  const float* z = (const float*)d_in[0];
  const float* p = (const float*)d_in[1];
  const float* c = (const float*)d_in[2];
  char* ws = (char*)d_ws;
  // layout: XA bf16 33.55MB | Cn 0.5MB | colsum 16KB | logC 16KB |
  //         rowv 16KB | S u8 67.1MB
  unsigned short* Xn = (unsigned short*)(ws);
  unsigned short* Cn = (unsigned short*)(ws + 33554432);
  float* colsum = (float*)(ws + 34078720);
  float* logC   = (float*)(ws + 34095104);
  float* rowv   = (float*)(ws + 34111488);
  unsigned char* S = (unsigned char*)(ws + 34127872);
  float* out = (float*)d_out;

  norm_rows_kernel<<<16640, 256, 0, stream>>>(z, p, c, Xn, Cn, colsum, out);
  gemm_s_kernel<<<1024, 256, 0, stream>>>(Xn, Cn, colsum, S);
  fin_logC_kernel<<<16, 256, 0, stream>>>(colsum, logC);
  pass2_mem_kernel<<<4096, 256, 0, stream>>>(S, logC, rowv);
  fin_reduce_kernel<<<16, 256, 0, stream>>>(rowv, out);
}